// Round 3
// baseline (14354.498 us; speedup 1.0000x reference)
//
#include <hip/hip_runtime.h>
#include <math.h>

#define DIM   768
#define NHEAD 16
#define DHEAD 48
#define NLAY  3
#define NTOK  256
#define BATCH 4
#define NPAST_ 16
#define NFUT  20
#define CCTX  273              // NTOK + 1 + NPAST
#define SMAXT 293              // CCTX + NFUT
#define MROWS 1172             // BATCH * SMAXT
#define NEGV  (-1.0e9f)
#define QKVPLANE 900096        // BATCH*NHEAD*SMAXT*48

typedef unsigned short u16;
typedef unsigned int   u32;
typedef __attribute__((ext_vector_type(8))) short short8;
typedef __attribute__((ext_vector_type(4))) float floatx4;

#if defined(__has_builtin)
#if __has_builtin(__builtin_amdgcn_global_load_lds)
#define USE_GLL 1
#endif
#endif
#ifndef USE_GLL
#define USE_GLL 0
#endif

__device__ inline u16 f2bf(float x) {
    union { float f; u32 u; } v; v.f = x;
    u32 r = v.u + 0x7fffu + ((v.u >> 16) & 1u);
    return (u16)(r >> 16);
}

__device__ inline float gelu_f(float x) {
    return 0.5f * x * (1.0f + erff(x * 0.70710678118654752f));
}

#if USE_GLL
__device__ inline void gll16(const u16* g, u16* l) {
    __builtin_amdgcn_global_load_lds((const __attribute__((address_space(1))) void*)g,
                                     (__attribute__((address_space(3))) void*)l, 16, 0, 0);
}
#endif

// ---------------------------------------------------------------- init X_base
__global__ void init_base(const float* __restrict__ img, const float* __restrict__ past,
                          const int* __restrict__ intent, const float* __restrict__ pos,
                          const float* __restrict__ futq, const float* __restrict__ iemb,
                          const float* __restrict__ temb, const float* __restrict__ Wp,
                          const float* __restrict__ bp, const float* __restrict__ Wpp,
                          const float* __restrict__ bpp, float* __restrict__ X)
{
    int r = blockIdx.x;
    int b = r / SMAXT, s = r % SMAXT;
    for (int j = threadIdx.x; j < DIM; j += blockDim.x) {
        float v;
        if (s < NTOK) {
            v = img[(long)(b * NTOK + s) * DIM + j] + pos[(long)s * DIM + j];
        } else if (s == NTOK) {
            int idx = intent[b] - 1; idx = idx < 0 ? 0 : (idx > 2 ? 2 : idx);
            v = iemb[(long)idx * DIM + j];
        } else if (s < CCTX) {
            int i = s - (NTOK + 1);
            v = bp[j] + bpp[j] + temb[(long)i * DIM + j];
            const float* pr = past + (long)(b * NPAST_ + i) * 6;
            #pragma unroll
            for (int c = 0; c < 6; ++c) v += pr[c] * Wp[(long)c * DIM + j];
            v += pr[0] * Wpp[j] + pr[1] * Wpp[DIM + j];
        } else {
            int f = s - CCTX;
            v = futq[(long)f * DIM + j] + temb[(long)(NPAST_ + f) * DIM + j];
        }
        X[(long)r * DIM + j] = v;
    }
}

// ---------------------------------------------------------------- per-row {sum, sumsq}
__launch_bounds__(256)
__global__ void row_stats(const float* __restrict__ x, float* __restrict__ st)
{
    int row = blockIdx.x * 4 + (threadIdx.x >> 6);
    int lane = threadIdx.x & 63;
    if (row >= MROWS) return;
    const float* xr = x + (long)row * DIM;
    float s = 0.f, q = 0.f;
    #pragma unroll
    for (int i = 0; i < 12; ++i) { float v = xr[lane + 64 * i]; s += v; q += v * v; }
    for (int off = 32; off; off >>= 1) { s += __shfl_down(s, off, 64); q += __shfl_down(q, off, 64); }
    if (!lane) { st[row * 2] = s; st[row * 2 + 1] = q; }
}

// ---------------------------------------------------------------- weight convert + transpose: W[K,N] fp32 -> Wt[N,K] bf16
__global__ void convert_transpose(const float* __restrict__ W, u16* __restrict__ Wt, int K, int N)
{
    __shared__ float tile[32][33];
    long lstride = (long)K * N;
    W  += blockIdx.z * lstride;
    Wt += blockIdx.z * lstride;
    int n0 = blockIdx.x * 32, k0 = blockIdx.y * 32;
    int tx = threadIdx.x & 31, ty = threadIdx.x >> 5;
    for (int i = ty; i < 32; i += 8)
        tile[i][tx] = W[(long)(k0 + i) * N + n0 + tx];
    __syncthreads();
    for (int i = ty; i < 32; i += 8)
        Wt[(long)(n0 + i) * K + k0 + tx] = f2bf(tile[tx][i]);
}

// ---------------------------------------------------------------- bf16 MFMA GEMM, BM=64, BK=64, double-buffered
// MODE 0: A bf16; out fp32 = acc+bias+res; accumulate {sum,sumsq} per row into statsAcc (atomic).
// MODE 1: A fp32 + fused LN (statsIn,g,b); relu -> bf16 out; zero zeroPtr.
// MODE 2: A fp32 + fused LN; out fp32 qkv-permuted [which][b*16+h][s][48], q pre-scaled; zero zeroPtr.
template<int BN, int MODE>
__launch_bounds__(256)
__global__ void gemm_mfma(const void* __restrict__ Av, const u16* __restrict__ Wt,
                          const float* __restrict__ bias, const float* __restrict__ res,
                          const float* __restrict__ statsIn, const float* __restrict__ gg,
                          const float* __restrict__ bb, float* __restrict__ statsAcc,
                          float* __restrict__ zeroPtr, void* __restrict__ outv,
                          int M, int N, int K)
{
    constexpr int NS = BN / 16;          // 8 or 4
    constexpr int NJ = NS / 2;           // cols/16 per wave
    __shared__ __align__(16) u16 As[2][64 * 64];
    __shared__ __align__(16) u16 Bs[2][BN * 64];

    int tid = threadIdx.x, lane = tid & 63, w = tid >> 6;
    int wm = w & 1, wn = w >> 1;
    int lm = lane & 15, lk = lane >> 4;
    int m0 = blockIdx.y * 64, n0 = blockIdx.x * BN;

    if (MODE != 0 && blockIdx.x == 0 && blockIdx.y == 0)
        for (int i2 = tid; i2 < 2 * MROWS; i2 += 256) zeroPtr[i2] = 0.f;

    // A-staging thread mapping: unit u = t*256 + tid
    int lmA = tid & 15, lkA = (tid >> 4) & 3, subA = tid >> 6;
    int rowA = subA * 16 + lmA;
    int grA = m0 + rowA; if (grA >= M) grA = M - 1;
    float meanA = 0.f, rstdA = 0.f;
    if (MODE != 0) {
        float su = statsIn[grA * 2], sq = statsIn[grA * 2 + 1];
        meanA = su * (1.f / 768.f);
        float var = sq * (1.f / 768.f) - meanA * meanA;
        rstdA = rsqrtf(var + 1e-5f);
    }
    const int KT = K >> 6;

    floatx4 acc[2][NJ];
    #pragma unroll
    for (int i = 0; i < 2; ++i)
        #pragma unroll
        for (int j = 0; j < NJ; ++j) acc[i][j] = (floatx4){0.f, 0.f, 0.f, 0.f};

    short8 ra[2];
#if !USE_GLL
    short8 rb[NS / 2];
#endif

    auto stage_a = [&](int k0) {
        #pragma unroll
        for (int t = 0; t < 2; ++t) {
            int kk = k0 + t * 32 + lkA * 8;
            if (MODE == 0) {
                ra[t] = *(const short8*)((const u16*)Av + (long)grA * K + kk);
            } else {
                const float* X = (const float*)Av;
                float4 x0 = *(const float4*)(X + (long)grA * K + kk);
                float4 x1 = *(const float4*)(X + (long)grA * K + kk + 4);
                float4 g0 = *(const float4*)(gg + kk);
                float4 g1 = *(const float4*)(gg + kk + 4);
                float4 b0 = *(const float4*)(bb + kk);
                float4 b1 = *(const float4*)(bb + kk + 4);
                short8 r;
                r[0] = (short)f2bf((x0.x - meanA) * rstdA * g0.x + b0.x);
                r[1] = (short)f2bf((x0.y - meanA) * rstdA * g0.y + b0.y);
                r[2] = (short)f2bf((x0.z - meanA) * rstdA * g0.z + b0.z);
                r[3] = (short)f2bf((x0.w - meanA) * rstdA * g0.w + b0.w);
                r[4] = (short)f2bf((x1.x - meanA) * rstdA * g1.x + b1.x);
                r[5] = (short)f2bf((x1.y - meanA) * rstdA * g1.y + b1.y);
                r[6] = (short)f2bf((x1.z - meanA) * rstdA * g1.z + b1.z);
                r[7] = (short)f2bf((x1.w - meanA) * rstdA * g1.w + b1.w);
                ra[t] = r;
            }
        }
    };
    auto write_a = [&](int cur) {
        #pragma unroll
        for (int t = 0; t < 2; ++t)
            *(short8*)&As[cur][(t * 256 + tid) * 8] = ra[t];
    };
#if USE_GLL
    auto stage_b = [&](int k0, int cur) {
        #pragma unroll
        for (int q = 0; q < NS / 2; ++q) {
            int idx = w * (NS / 2) + q;
            int t = idx / NS, sub = idx % NS;
            const u16* gp = Wt + (long)(n0 + sub * 16 + lm) * K + k0 + t * 32 + lk * 8;
            gll16(gp, &Bs[cur][(t * NS + sub) * 512]);
        }
    };
#else
    auto stage_b = [&](int k0) {
        #pragma unroll
        for (int q = 0; q < NS / 2; ++q) {
            int u = q * 256 + tid;
            int hi = u >> 6;                 // t*NS+sub
            int t = hi / NS, sub = hi % NS;
            int lkB = (u >> 4) & 3, lmB = u & 15;
            rb[q] = *(const short8*)(Wt + (long)(n0 + sub * 16 + lmB) * K + k0 + t * 32 + lkB * 8);
        }
    };
    auto write_b = [&](int cur) {
        #pragma unroll
        for (int q = 0; q < NS / 2; ++q)
            *(short8*)&Bs[cur][(q * 256 + tid) * 8] = rb[q];
    };
#endif

    // prologue
    stage_a(0);
#if USE_GLL
    stage_b(0, 0);
#else
    stage_b(0);
#endif
    write_a(0);
#if !USE_GLL
    write_b(0);
#endif
    __syncthreads();

    for (int k = 0; k < KT; ++k) {
        int cur = k & 1, nxt = cur ^ 1;
        bool more = (k + 1 < KT);
        if (more) {
            stage_a((k + 1) << 6);
#if USE_GLL
            stage_b((k + 1) << 6, nxt);
#else
            stage_b((k + 1) << 6);
#endif
        }
        #pragma unroll
        for (int t = 0; t < 2; ++t) {
            short8 af[2];
            #pragma unroll
            for (int i = 0; i < 2; ++i)
                af[i] = *(const short8*)&As[cur][((((t * 4 + wm * 2 + i) * 4 + lk) * 16) + lm) * 8];
            short8 bfr[NJ];
            #pragma unroll
            for (int j = 0; j < NJ; ++j)
                bfr[j] = *(const short8*)&Bs[cur][((((t * NS + wn * NJ + j) * 4 + lk) * 16) + lm) * 8];
            #pragma unroll
            for (int i = 0; i < 2; ++i)
                #pragma unroll
                for (int j = 0; j < NJ; ++j)
                    acc[i][j] = __builtin_amdgcn_mfma_f32_16x16x32_bf16(af[i], bfr[j], acc[i][j], 0, 0, 0);
        }
        if (more) {
            write_a(nxt);
#if !USE_GLL
            write_b(nxt);
#endif
        }
        __syncthreads();
    }

    // epilogue
    #pragma unroll
    for (int i = 0; i < 2; ++i) {
        #pragma unroll
        for (int rr = 0; rr < 4; ++rr) {
            int row = m0 + wm * 32 + i * 16 + lk * 4 + rr;
            float s1 = 0.f, s2 = 0.f;
            #pragma unroll
            for (int j = 0; j < NJ; ++j) {
                int col = n0 + wn * (NJ * 16) + j * 16 + lm;
                float val = acc[i][j][rr] + bias[col];
                if (row < M) {
                    if (MODE == 0) {
                        val += res[(long)row * N + col];
                        ((float*)outv)[(long)row * N + col] = val;
                        s1 += val; s2 += val * val;
                    } else if (MODE == 1) {
                        ((u16*)outv)[(long)row * N + col] = f2bf(fmaxf(val, 0.f));
                    } else {
                        int which = col >= 1536 ? 2 : (col >= 768 ? 1 : 0);
                        int rem = col - which * 768;
                        int h = rem / 48, d = rem - h * 48;
                        if (which == 0) val *= 0.14433756729740643f;
                        int b2 = row / SMAXT, s = row - b2 * SMAXT;
                        ((float*)outv)[(long)which * QKVPLANE + ((long)(b2 * 16 + h) * SMAXT + s) * 48 + d] = val;
                    }
                }
            }
            if (MODE == 0) {
                #pragma unroll
                for (int m = 1; m < 16; m <<= 1) {
                    s1 += __shfl_xor(s1, m, 16);
                    s2 += __shfl_xor(s2, m, 16);
                }
                if (lm == 0 && row < M) {
                    atomicAdd(&statsAcc[row * 2], s1);
                    atomicAdd(&statsAcc[row * 2 + 1], s2);
                }
            }
        }
    }
}

// ---------------------------------------------------------------- attention (fp32, head-major qkv, q pre-scaled)
__launch_bounds__(256)
__global__ void attn_kernel(const float* __restrict__ qkv, u16* __restrict__ o, int S)
{
    int bh = blockIdx.y;
    int b = bh >> 4, h = bh & 15;
    int q0 = blockIdx.x * 16;
    if (q0 >= S) return;
    __shared__ float qs[16][48];
    __shared__ float kbuf[3328];
    __shared__ float sc[16][304];
    int t = threadIdx.x;
    const float* qp = qkv + (long)bh * SMAXT * 48;
    const float* kp = qp + QKVPLANE;
    const float* vp = qp + 2 * QKVPLANE;

    for (int lin = t; lin < 16 * 48; lin += 256) {
        int i2 = lin / 48, d = lin % 48;
        int qi2 = q0 + i2; if (qi2 > S - 1) qi2 = S - 1;
        qs[i2][d] = qp[(long)qi2 * 48 + d];
    }
    __syncthreads();
    int i = t >> 4, j = t & 15;
    int qi = q0 + i;
    float4 q4[12];
    #pragma unroll
    for (int k4 = 0; k4 < 12; ++k4) q4[k4] = *(const float4*)&qs[i][k4 * 4];

    for (int s0 = 0; s0 < S; s0 += 64) {
        int ns = S - s0; if (ns > 64) ns = 64;
        __syncthreads();
        for (int lin = t; lin < 64 * 12; lin += 256) {
            int ss = lin / 12, d4 = lin % 12;
            float4 kv = make_float4(0.f, 0.f, 0.f, 0.f);
            if (ss < ns) kv = *(const float4*)(kp + (long)(s0 + ss) * 48 + d4 * 4);
            *(float4*)&kbuf[ss * 52 + d4 * 4] = kv;
        }
        __syncthreads();
        #pragma unroll
        for (int u = 0; u < 4; ++u) {
            int ss = j + 16 * u;
            float acc = 0.f;
            #pragma unroll
            for (int k4 = 0; k4 < 12; ++k4) {
                float4 kk = *(const float4*)&kbuf[ss * 52 + k4 * 4];
                acc += q4[k4].x * kk.x + q4[k4].y * kk.y + q4[k4].z * kk.z + q4[k4].w * kk.w;
            }
            int s = s0 + ss;
            if (ss < ns) {
                bool masked = (qi >= CCTX) && (s > qi);
                sc[i][s] = masked ? acc + NEGV : acc;
            }
        }
    }
    __syncthreads();

    float mx = -1e30f;
    for (int s = j; s < S; s += 16) mx = fmaxf(mx, sc[i][s]);
    #pragma unroll
    for (int m = 8; m; m >>= 1) mx = fmaxf(mx, __shfl_xor(mx, m, 16));
    int Sp = (S + 3) & ~3;
    float sum = 0.f;
    for (int s = j; s < Sp; s += 16) {
        float e = (s < S) ? __expf(sc[i][s] - mx) : 0.f;
        sc[i][s] = e; sum += e;
    }
    #pragma unroll
    for (int m = 8; m; m >>= 1) sum += __shfl_xor(sum, m, 16);
    float inv = 1.f / sum;

    float oc0 = 0.f, oc1 = 0.f, oc2 = 0.f;
    int d0 = j * 3;
    for (int s0 = 0; s0 < S; s0 += 64) {
        int ns4 = Sp - s0; if (ns4 > 64) ns4 = 64;
        __syncthreads();
        for (int lin = t; lin < 64 * 48; lin += 256) {
            int ss = lin / 48, d = lin % 48;
            float v = 0.f;
            int s = s0 + ss;
            if (s < S) v = vp[(long)s * 48 + d];
            kbuf[d * 68 + ss] = v;
        }
        __syncthreads();
        for (int sb = 0; sb < ns4; sb += 4) {
            float4 a4 = *(const float4*)&sc[i][s0 + sb];
            float4 v0 = *(const float4*)&kbuf[d0 * 68 + sb];
            float4 v1 = *(const float4*)&kbuf[(d0 + 1) * 68 + sb];
            float4 v2 = *(const float4*)&kbuf[(d0 + 2) * 68 + sb];
            oc0 += a4.x * v0.x + a4.y * v0.y + a4.z * v0.z + a4.w * v0.w;
            oc1 += a4.x * v1.x + a4.y * v1.y + a4.z * v1.z + a4.w * v1.w;
            oc2 += a4.x * v2.x + a4.y * v2.y + a4.z * v2.z + a4.w * v2.w;
        }
    }
    if (qi < S) {
        u16* orow = o + ((long)(b * SMAXT + qi)) * 768 + h * 48 + d0;
        orow[0] = f2bf(oc0 * inv); orow[1] = f2bf(oc1 * inv); orow[2] = f2bf(oc2 * inv);
    }
}

// ---------------------------------------------------------------- decoder gelu GEMM (4x768 @ 768x768), fp32
__launch_bounds__(256)
__global__ void dec_gelu(const float* __restrict__ src, long srowstride,
                         const float* __restrict__ W, const float* __restrict__ bias,
                         float* __restrict__ dst)
{
    int b = blockIdx.y;
    int jb = blockIdx.x;
    __shared__ float s0buf[768];
    __shared__ float red[4][64];
    int tid = threadIdx.x;
    const float* sr = src + (long)b * srowstride;
    for (int i = tid; i < 768; i += 256) s0buf[i] = sr[i];
    __syncthreads();
    int jj = tid & 63, ig = tid >> 6;
    int jcol = jb * 64 + jj;
    float acc = 0.f;
    const float* wp = W + (long)(ig * 192) * 768 + jcol;
    #pragma unroll 4
    for (int i = 0; i < 192; ++i) acc += s0buf[ig * 192 + i] * wp[(long)i * 768];
    red[ig][jj] = acc;
    __syncthreads();
    if (ig == 0) {
        float a = red[0][jj] + red[1][jj] + red[2][jj] + red[3][jj] + bias[jcol];
        dst[(long)b * 768 + jcol] = gelu_f(a);
    }
}

// ---------------------------------------------------------------- decoder final (+ incremental Xb stats)
__launch_bounds__(256)
__global__ void dec_final(const float* __restrict__ d2, const float* __restrict__ Wd3,
                          const float* __restrict__ bd3, const float* __restrict__ Wpp,
                          const float* __restrict__ bpp, const float* __restrict__ gpp,
                          const float* __restrict__ bepp, float* __restrict__ out,
                          float* __restrict__ X, float* __restrict__ statsXb, int t)
{
    int b = blockIdx.x;
    int tid = threadIdx.x;
    __shared__ float red[2][4];
    __shared__ float pp[2];
    const float* dr = d2 + (long)b * 768;
    float a0 = 0.f, a1 = 0.f;
    for (int i = tid; i < 768; i += 256) {
        float v = dr[i];
        a0 += v * Wd3[2 * i]; a1 += v * Wd3[2 * i + 1];
    }
    for (int off = 32; off; off >>= 1) { a0 += __shfl_down(a0, off, 64); a1 += __shfl_down(a1, off, 64); }
    int wid = tid >> 6, lane = tid & 63;
    if (!lane) { red[0][wid] = a0; red[1][wid] = a1; }
    __syncthreads();
    if (!tid) {
        float p0 = red[0][0] + red[0][1] + red[0][2] + red[0][3] + bd3[0];
        float p1 = red[1][0] + red[1][1] + red[1][2] + red[1][3] + bd3[1];
        out[(long)(b * NFUT + t) * 2 + 0] = p0;
        out[(long)(b * NFUT + t) * 2 + 1] = p1;
        pp[0] = p0; pp[1] = p1;
    }
    __syncthreads();
    if (t == NFUT - 1) return;
    float p0 = pp[0], p1 = pp[1];
    float pv[3]; float s = 0.f;
    #pragma unroll
    for (int u = 0; u < 3; ++u) {
        int jcol = tid + 256 * u;
        pv[u] = p0 * Wpp[jcol] + p1 * Wpp[768 + jcol] + bpp[jcol];
        s += pv[u];
    }
    for (int off = 32; off; off >>= 1) s += __shfl_down(s, off, 64);
    __syncthreads();
    if (!lane) red[0][wid] = s;
    __syncthreads();
    float mean = (red[0][0] + red[0][1] + red[0][2] + red[0][3]) * (1.f / 768.f);
    float vs = 0.f;
    #pragma unroll
    for (int u = 0; u < 3; ++u) { float d = pv[u] - mean; vs += d * d; }
    for (int off = 32; off; off >>= 1) vs += __shfl_down(vs, off, 64);
    __syncthreads();
    if (!lane) red[1][wid] = vs;
    __syncthreads();
    float var = (red[1][0] + red[1][1] + red[1][2] + red[1][3]) * (1.f / 768.f);
    float inv = rsqrtf(var + 1e-5f);
    int r = b * SMAXT + CCTX + t + 1;
    float* Xr = X + (long)r * 768;
    float nv[3];
    #pragma unroll
    for (int u = 0; u < 3; ++u) {
        int jcol = tid + 256 * u;
        float y = (pv[u] - mean) * inv * gpp[jcol] + bepp[jcol];
        float xv = Xr[jcol];
        if (y > 0.f) xv += y;
        Xr[jcol] = xv;
        nv[u] = xv;
    }
    float s1 = nv[0] + nv[1] + nv[2];
    float s2 = nv[0] * nv[0] + nv[1] * nv[1] + nv[2] * nv[2];
    for (int off = 32; off; off >>= 1) { s1 += __shfl_down(s1, off, 64); s2 += __shfl_down(s2, off, 64); }
    __syncthreads();
    if (!lane) { red[0][wid] = s1; red[1][wid] = s2; }
    __syncthreads();
    if (!tid) {
        statsXb[r * 2]     = red[0][0] + red[0][1] + red[0][2] + red[0][3];
        statsXb[r * 2 + 1] = red[1][0] + red[1][1] + red[1][2] + red[1][3];
    }
}

// ---------------------------------------------------------------- launch
extern "C" void kernel_launch(void* const* d_in, const int* in_sizes, int n_in,
                              void* d_out, int out_size, void* d_ws, size_t ws_size,
                              hipStream_t stream)
{
    const float* img    = (const float*)d_in[0];
    const float* past   = (const float*)d_in[1];
    const int*   intent = (const int*)d_in[2];
    const float* pos    = (const float*)d_in[3];
    const float* futq   = (const float*)d_in[4];
    const float* iemb   = (const float*)d_in[5];
    const float* temb   = (const float*)d_in[6];
    const float* W_past = (const float*)d_in[7];
    const float* b_past = (const float*)d_in[8];
    const float* W_ppos = (const float*)d_in[9];
    const float* b_ppos = (const float*)d_in[10];
    const float* W_pp   = (const float*)d_in[11];
    const float* b_pp   = (const float*)d_in[12];
    const float* g_pp   = (const float*)d_in[13];
    const float* be_pp  = (const float*)d_in[14];
    const float* Wqkv   = (const float*)d_in[15];
    const float* bqkv   = (const float*)d_in[16];
    const float* Wo     = (const float*)d_in[17];
    const float* bo     = (const float*)d_in[18];
    const float* g1     = (const float*)d_in[19];
    const float* beta1  = (const float*)d_in[20];
    const float* g2     = (const float*)d_in[21];
    const float* beta2  = (const float*)d_in[22];
    const float* W1     = (const float*)d_in[23];
    const float* bf1    = (const float*)d_in[24];
    const float* W2     = (const float*)d_in[25];
    const float* bf2    = (const float*)d_in[26];
    const float* Wd1    = (const float*)d_in[27];
    const float* bd1    = (const float*)d_in[28];
    const float* Wd2    = (const float*)d_in[29];
    const float* bd2    = (const float*)d_in[30];
    const float* Wd3    = (const float*)d_in[31];
    const float* bd3    = (const float*)d_in[32];
    float* out = (float*)d_out;

    float* ws     = (float*)d_ws;
    float* Xb     = ws;                      // 900096 f
    float* xbuf   = ws + 900096;             // 900096 f
    float* qkvbuf = ws + 1800192;            // 2700288 f
    float* statsXb = ws + 4500480;           // 2344 f
    float* stats1  = ws + 4504576;           // 2344 f
    float* stats2  = ws + 4508672;           // 2344 f
    u16*   aobuf  = (u16*)(ws + 4950528);    // 900096 bf16
    u16*   big    = (u16*)(ws + 5400576);    // 1172*3072 bf16
    float* d1ws   = ws + 7200768;            // 3072 f
    float* d2ws   = ws + 7203840;            // 3072 f
    u16*   WqkvT  = (u16*)(ws + 7206912);
    u16*   WoT    = (u16*)(ws + 9861120);
    u16*   W1T    = (u16*)(ws + 10745856);
    u16*   W2T    = (u16*)(ws + 14284800);

    convert_transpose<<<dim3(2304/32, 768/32, 3), 256, 0, stream>>>(Wqkv, WqkvT, 768, 2304);
    convert_transpose<<<dim3(768/32, 768/32, 3), 256, 0, stream>>>(Wo, WoT, 768, 768);
    convert_transpose<<<dim3(3072/32, 768/32, 3), 256, 0, stream>>>(W1, W1T, 768, 3072);
    convert_transpose<<<dim3(768/32, 3072/32, 3), 256, 0, stream>>>(W2, W2T, 3072, 768);

    init_base<<<dim3(MROWS), dim3(256), 0, stream>>>(img, past, intent, pos, futq, iemb,
                                                     temb, W_past, b_past, W_ppos, b_ppos, Xb);
    row_stats<<<dim3(293), dim3(256), 0, stream>>>(Xb, statsXb);

    for (int t = 0; t < NFUT; ++t) {
        int S = CCTX + t + 1;
        const float* src = Xb;
        for (int l = 0; l < NLAY; ++l) {
            const float* sIn = (l == 0) ? statsXb : stats1;
            // QKV (LN1 fused), zeroes stats2
            gemm_mfma<128, 2><<<dim3(18, 19), dim3(256), 0, stream>>>(
                src, WqkvT + (long)l * 768 * 2304, bqkv + l * 2304, nullptr,
                sIn, g1 + l * 768, beta1 + l * 768, nullptr, stats2, qkvbuf, MROWS, 2304, 768);
            attn_kernel<<<dim3((S + 15) / 16, 64), dim3(256), 0, stream>>>(qkvbuf, aobuf, S);
            // Wo + residual, accumulates stats2 (LN2 input)
            gemm_mfma<64, 0><<<dim3(12, 19), dim3(256), 0, stream>>>(
                aobuf, WoT + (long)l * 768 * 768, bo + l * 768, src,
                nullptr, nullptr, nullptr, stats2, nullptr, xbuf, MROWS, 768, 768);
            // FFN1 (LN2 fused), relu->bf16, zeroes stats1
            gemm_mfma<128, 1><<<dim3(24, 19), dim3(256), 0, stream>>>(
                xbuf, W1T + (long)l * 768 * 3072, bf1 + l * 3072, nullptr,
                stats2, g2 + l * 768, beta2 + l * 768, nullptr, stats1, big, MROWS, 3072, 768);
            // FFN2 + residual, accumulates stats1 (next layer LN1 input)
            gemm_mfma<64, 0><<<dim3(12, 19), dim3(256), 0, stream>>>(
                big, W2T + (long)l * 3072 * 768, bf2 + l * 768, xbuf,
                nullptr, nullptr, nullptr, stats1, nullptr, xbuf, MROWS, 768, 3072);
            src = xbuf;
        }
        dec_gelu<<<dim3(12, 4), dim3(256), 0, stream>>>(xbuf + (long)(S - 1) * 768, (long)SMAXT * 768, Wd1, bd1, d1ws);
        dec_gelu<<<dim3(12, 4), dim3(256), 0, stream>>>(d1ws, 768L, Wd2, bd2, d2ws);
        dec_final<<<dim3(4), dim3(256), 0, stream>>>(d2ws, Wd3, bd3, W_pp, b_pp, g_pp, be_pp, out, Xb, statsXb, t);
    }
}